// Round 14
// baseline (12604.896 us; speedup 1.0000x reference)
//
#include <hip/hip_runtime.h>
#include <hip/hip_bf16.h>
#include <cstdint>

#define M_TOT 16384
#define K_TOT 4096
#define N_TOT 4096
#define RNK   16
#define BM 256
#define BN 256
#define BK 32
#define NTK (K_TOT / BK)   // 128 K-tiles

using bf16x8 = __attribute__((ext_vector_type(8))) __bf16;
using f32x16 = __attribute__((ext_vector_type(16))) float;

__device__ __forceinline__ unsigned short f2bf(float f) {
  union { float f; unsigned u; } v; v.f = f;
  unsigned u = v.u;
  unsigned r = (u + 0x7fffu + ((u >> 16) & 1u)) >> 16;
  return (unsigned short)r;
}

// ---------------- f32 -> bf16 conversion (W) --------------------------------
__global__ void cvt_f32_bf16(const float* __restrict__ in,
                             unsigned short* __restrict__ out, int n4) {
  int i = blockIdx.x * blockDim.x + threadIdx.x;
  int stride = gridDim.x * blockDim.x;
  for (; i < n4; i += stride) {
    float4 v = reinterpret_cast<const float4*>(in)[i];
    ushort4 o;
    o.x = f2bf(v.x); o.y = f2bf(v.y); o.z = f2bf(v.z); o.w = f2bf(v.w);
    reinterpret_cast<ushort4*>(out)[i] = o;
  }
}

// ------ fused: xb = bf16(x) (all lanes, vectorized) THEN inter from xb ------
__global__ __launch_bounds__(256) void xcvt_inter_kernel(
    const float* __restrict__ x, const int* __restrict__ eid,
    const float* __restrict__ la, unsigned short* __restrict__ xb,
    float* __restrict__ inter) {
  const int row0 = blockIdx.x * 8;
  const int t = threadIdx.x;

  const float4* xs = reinterpret_cast<const float4*>(x + (size_t)row0 * K_TOT);
  ushort4* xd = reinterpret_cast<ushort4*>(xb + (size_t)row0 * K_TOT);
#pragma unroll
  for (int i = 0; i < 32; ++i) {
    float4 v = xs[t + 256 * i];
    ushort4 o;
    o.x = f2bf(v.x); o.y = f2bf(v.y); o.z = f2bf(v.z); o.w = f2bf(v.w);
    xd[t + 256 * i] = o;
  }
  __syncthreads();   // compiler drains vmcnt(0) before the barrier

  const int e = eid[row0 >> 11];
  const int r = t >> 4;
  const int j = t & 15;
  const float* lar = la + ((size_t)e * RNK + r) * K_TOT;
  const unsigned short* xr = xb + (size_t)row0 * K_TOT;
  float acc[8] = {0.f,0.f,0.f,0.f,0.f,0.f,0.f,0.f};
  union bu { unsigned u; float f; };
  for (int c = 0; c < K_TOT / 128; ++c) {
    int k = c * 128 + j * 8;
    float4 la0 = *reinterpret_cast<const float4*>(lar + k);
    float4 la1 = *reinterpret_cast<const float4*>(lar + k + 4);
#pragma unroll
    for (int q = 0; q < 8; ++q) {
      uint4 u = *reinterpret_cast<const uint4*>(xr + (size_t)q * K_TOT + k);
      bu a, b;
      float s;
      a.u = u.x << 16; b.u = u.x & 0xffff0000u;
      s  = a.f * la0.x + b.f * la0.y;
      a.u = u.y << 16; b.u = u.y & 0xffff0000u;
      s += a.f * la0.z + b.f * la0.w;
      a.u = u.z << 16; b.u = u.z & 0xffff0000u;
      s += a.f * la1.x + b.f * la1.y;
      a.u = u.w << 16; b.u = u.w & 0xffff0000u;
      s += a.f * la1.z + b.f * la1.w;
      acc[q] += s;
    }
  }
#pragma unroll
  for (int q = 0; q < 8; ++q) {
    float a = acc[q];
    a += __shfl_xor(a, 1);
    a += __shfl_xor(a, 2);
    a += __shfl_xor(a, 4);
    a += __shfl_xor(a, 8);
    acc[q] = a;
  }
  if (j == 0) {
#pragma unroll
    for (int q = 0; q < 8; ++q)
      inter[(size_t)(row0 + q) * RNK + r] = acc[q];
  }
}

// -- 256x256 GEMM, BK=32 dbuf (64KB LDS, 2 blocks/CU), 32x32x16 MFMA ---------
#define GLD16(gsrc, ldst)                                                      \
  __builtin_amdgcn_global_load_lds(                                            \
      (__attribute__((address_space(1))) const void*)(gsrc),                   \
      (__attribute__((address_space(3))) void*)(ldst), 16, 0, 0)

#define FENCE() asm volatile("" ::: "memory")
#define BARRIER() do { FENCE(); __builtin_amdgcn_s_barrier(); FENCE(); } while (0)

// stage K-tile T (A 256x32 = 16KB + B 256x32 = 16KB) -> buf[T&1]; 4 GLD16.
#define STAGE(T) do {                                                          \
  const int _b = ((T) & 1) << 15;                                              \
  const size_t _go = (size_t)(T) * BK;                                         \
  GLD16(gA + _go,                       smem + _b + ldsw);                     \
  GLD16(gA + (size_t)128 * K_TOT + _go, smem + _b + 8192 + ldsw);              \
  GLD16(gB + _go,                       smem + _b + 16384 + ldsw);             \
  GLD16(gB + (size_t)128 * K_TOT + _go, smem + _b + 24576 + ldsw);             \
} while (0)

__global__ __launch_bounds__(512, 4) void gemm_kernel(
    const unsigned short* __restrict__ xb, const unsigned short* __restrict__ wb,
    const float* __restrict__ bias, const float* __restrict__ inter,
    const float* __restrict__ lb, const int* __restrict__ eid,
    float* __restrict__ out) {
  __shared__ unsigned char smem[65536];   // 2 bufs x (A 16KB + B 16KB)

  const int bid = blockIdx.x;
  const int swz = (bid & 7) * 128 + (bid >> 3);   // 1024 wgs, bijective
  const int bm = swz >> 4, bn = swz & 15;         // bm-major (best FETCH map)
  const int brow = bm * BM, bcol = bn * BN;
  const int t = threadIdx.x;
  const int w = t >> 6, l = t & 63;
  const int wr = w >> 2, wc = w & 3;              // 2 x 4 wave grid, wave = 128x64 out
  const int l31 = l & 31;
  const int l32 = l >> 5;
  const int lsw = (l >> 1) & 3;                   // f(row) = (row>>1)&3

  // staging source (pre-swizzled inverse of ds_read swizzle; rule 21).
  // GLD row = t>>2 (+128 for 2nd call: bits 1-2 unchanged) -> f = (t>>3)&3.
  const int srow = t >> 2;
  const int scol = ((t & 3) ^ ((t >> 3) & 3)) << 3;
  const unsigned short* gA = xb + (size_t)(brow + srow) * K_TOT + scol;
  const unsigned short* gB = wb + (size_t)(bcol + srow) * K_TOT + scol;
  const int ldsw = w << 10;                       // 8 waves x 1KB per 8KB call

  f32x16 acc[4][2];
#pragma unroll
  for (int i = 0; i < 4; ++i)
#pragma unroll
    for (int n = 0; n < 2; ++n)
#pragma unroll
      for (int r = 0; r < 16; ++r)
        acc[i][n][r] = 0.f;
  bf16x8 aF[4][2], bF[2][2];

  // prologue: stage tile 0 (tile 1 staged inside iteration 0).
  STAGE(0);

  for (int T = 0; T < NTK; ++T) {
    const int bo = (T & 1) << 15;
    if (T + 1 < NTK) {
      STAGE(T + 1);                                   // -> other buffer (safe)
      asm volatile("s_waitcnt vmcnt(4)" ::: "memory");  // retire tile T's 4
    } else {
      asm volatile("s_waitcnt vmcnt(0)" ::: "memory");
    }
    BARRIER();
    // fragment reads: row-major 64B rows, swizzled 16B slot
#pragma unroll
    for (int ar = 0; ar < 4; ++ar)
#pragma unroll
      for (int ks = 0; ks < 2; ++ks)
        aF[ar][ks] = *reinterpret_cast<const bf16x8*>(
            smem + bo + (wr * 128 + ar * 32 + l31) * 64 +
            ((((ks << 1) + l32) ^ lsw) << 4));
#pragma unroll
    for (int n = 0; n < 2; ++n)
#pragma unroll
      for (int ks = 0; ks < 2; ++ks)
        bF[n][ks] = *reinterpret_cast<const bf16x8*>(
            smem + bo + 16384 + (wc * 64 + n * 32 + l31) * 64 +
            ((((ks << 1) + l32) ^ lsw) << 4));
    __builtin_amdgcn_s_setprio(1);
#pragma unroll
    for (int ar = 0; ar < 4; ++ar)
#pragma unroll
      for (int n = 0; n < 2; ++n) {
        acc[ar][n] = __builtin_amdgcn_mfma_f32_32x32x16_bf16(
            aF[ar][0], bF[n][0], acc[ar][n], 0, 0, 0);
        acc[ar][n] = __builtin_amdgcn_mfma_f32_32x32x16_bf16(
            aF[ar][1], bF[n][1], acc[ar][n], 0, 0, 0);
      }
    __builtin_amdgcn_s_setprio(0);
    BARRIER();   // all reads of buf[T&1] done before iteration T+1 stages T+2
  }

  // ---------------- epilogue: bias + 2.0 * inter @ lb^T ----------------
  float* interS = reinterpret_cast<float*>(smem);           // 256 x 16 f32 (broadcast)
  float* lbS    = reinterpret_cast<float*>(smem + 16384);   // 256 x 17 f32 (padded)
  const int e = eid[brow >> 11];
  const float* interG = inter + (size_t)brow * RNK;
  const float* lbG    = lb + ((size_t)e * N_TOT + bcol) * RNK;
#pragma unroll
  for (int q = 0; q < 8; ++q) {
    const int idx = t + 512 * q;
    interS[idx] = interG[idx];
    lbS[(idx >> 4) * 17 + (idx & 15)] = lbG[idx];
  }
  __syncthreads();

  // C/D layout (32x32): col = lane&31, row = (r&3) + 8*(r>>2) + 4*(lane>>5)
  const int ccol = wc * 64 + l31;
  float bv[2];
#pragma unroll
  for (int n = 0; n < 2; ++n)
    bv[n] = bias[bcol + ccol + n * 32];

#pragma unroll
  for (int ar = 0; ar < 4; ++ar) {
#pragma unroll
    for (int r = 0; r < 16; ++r) {
      const int ml = wr * 128 + ar * 32 + (r & 3) + 8 * (r >> 2) + 4 * l32;
      const float* iv = interS + ml * RNK;
      const size_t orow = (size_t)(brow + ml) * N_TOT + bcol;
#pragma unroll
      for (int n = 0; n < 2; ++n) {
        const int ol = ccol + n * 32;
        const float* lv = lbS + ol * 17;
        float d = 0.f;
#pragma unroll
        for (int rr = 0; rr < RNK; ++rr) d += iv[rr] * lv[rr];
        out[orow + ol] = acc[ar][n][r] + bv[n] + 2.0f * d;
      }
    }
  }
}

extern "C" void kernel_launch(void* const* d_in, const int* in_sizes, int n_in,
                              void* d_out, int out_size, void* d_ws, size_t ws_size,
                              hipStream_t stream) {
  const float* x    = (const float*)d_in[0];
  const int*   eid  = (const int*)d_in[1];
  const float* W    = (const float*)d_in[2];
  const float* bias = (const float*)d_in[3];
  const float* la   = (const float*)d_in[4];
  const float* lb   = (const float*)d_in[5];
  float* out = (float*)d_out;

  // workspace layout: xb (134MB) | wb (33.5MB) | inter (1MB)
  unsigned short* xb = (unsigned short*)d_ws;
  unsigned short* wb = xb + (size_t)M_TOT * K_TOT;
  float* inter = (float*)(wb + (size_t)N_TOT * K_TOT);

  cvt_f32_bf16<<<2048, 256, 0, stream>>>(W, wb, (N_TOT * K_TOT) / 4);
  xcvt_inter_kernel<<<M_TOT / 8, 256, 0, stream>>>(x, eid, la, xb, inter);

  gemm_kernel<<<(M_TOT / BM) * (N_TOT / BN), 512, 0, stream>>>(
      xb, wb, bias, inter, lb, eid, out);
}

// Round 15
// 828.212 us; speedup vs baseline: 15.2194x; 15.2194x over previous
//
#include <hip/hip_runtime.h>
#include <hip/hip_bf16.h>
#include <cstdint>

#define M_TOT 16384
#define K_TOT 4096
#define N_TOT 4096
#define RNK   16
#define BM 256
#define BN 256
#define BK 64
#define NTK (K_TOT / BK)   // 64 K-tiles

using bf16x8 = __attribute__((ext_vector_type(8))) __bf16;
using f32x16 = __attribute__((ext_vector_type(16))) float;

__device__ __forceinline__ unsigned short f2bf(float f) {
  union { float f; unsigned u; } v; v.f = f;
  unsigned u = v.u;
  unsigned r = (u + 0x7fffu + ((u >> 16) & 1u)) >> 16;
  return (unsigned short)r;
}

// ---- fused aux: blocks [0,2048): xb = bf16(x) + inter (in-register);    ----
// ----            blocks [2048,3072): wb = bf16(W)                        ----
__global__ __launch_bounds__(256) void aux_kernel(
    const float* __restrict__ x, const int* __restrict__ eid,
    const float* __restrict__ la, const float* __restrict__ W,
    unsigned short* __restrict__ xb, unsigned short* __restrict__ wb,
    float* __restrict__ inter) {
  const int bid = blockIdx.x;
  const int t = threadIdx.x;
  if (bid < 2048) {
    // 8 rows per block; thread (q = t>>5, c = t&31) covers row row0+q,
    // float4 slots j = c + 32*i. All lanes convert+store (coalesced per row);
    // inter partials accumulate in-register from the same f32 data.
    const int row0 = bid * 8;
    const int q = t >> 5, c = t & 31;
    const int row = row0 + q;
    const float4* xr = reinterpret_cast<const float4*>(x + (size_t)row * K_TOT);
    ushort4* xw = reinterpret_cast<ushort4*>(xb + (size_t)row * K_TOT);
    const int e = eid[row0 >> 11];
    const float4* la4 = reinterpret_cast<const float4*>(la + (size_t)e * RNK * K_TOT);
    float pacc[RNK];
#pragma unroll
    for (int r = 0; r < RNK; ++r) pacc[r] = 0.f;
    for (int i = 0; i < 32; ++i) {
      const int j = c + 32 * i;
      float4 v = xr[j];
      ushort4 o;
      o.x = f2bf(v.x); o.y = f2bf(v.y); o.z = f2bf(v.z); o.w = f2bf(v.w);
      xw[j] = o;
#pragma unroll
      for (int r = 0; r < RNK; ++r) {
        float4 l4 = la4[r * (K_TOT / 4) + j];   // L2-hot (la[e] = 256KB)
        pacc[r] += v.x * l4.x + v.y * l4.y + v.z * l4.z + v.w * l4.w;
      }
    }
    // reduce over the 32 lanes (bits 0-4 of lane id) of this row
#pragma unroll
    for (int r = 0; r < RNK; ++r) {
      float a = pacc[r];
      a += __shfl_xor(a, 1);
      a += __shfl_xor(a, 2);
      a += __shfl_xor(a, 4);
      a += __shfl_xor(a, 8);
      a += __shfl_xor(a, 16);
      pacc[r] = a;
    }
    if (c == 0) {
#pragma unroll
      for (int r = 0; r < RNK; ++r)
        inter[(size_t)row * RNK + r] = pacc[r];
    }
  } else {
    // W conversion: 1024 blocks x 256 thr x 16 float4 = 4M float4
    const int base = (bid - 2048) * 4096;
    const float4* ws = reinterpret_cast<const float4*>(W);
    ushort4* wd = reinterpret_cast<ushort4*>(wb);
#pragma unroll
    for (int i = 0; i < 16; ++i) {
      const int j = base + t + 256 * i;
      float4 v = ws[j];
      ushort4 o;
      o.x = f2bf(v.x); o.y = f2bf(v.y); o.z = f2bf(v.z); o.w = f2bf(v.w);
      wd[j] = o;
    }
  }
}

// ---------- 256x256 8-phase GEMM, 32x32x16 MFMA + fused LoRA epilogue -------
// (exact r11 kernel -- best measured: gemm 663 us / 829 TF)
#define GLD16(gsrc, ldst)                                                      \
  __builtin_amdgcn_global_load_lds(                                            \
      (__attribute__((address_space(1))) const void*)(gsrc),                   \
      (__attribute__((address_space(3))) void*)(ldst), 16, 0, 0)

#define FENCE() asm volatile("" ::: "memory")
#define BARRIER() do { FENCE(); __builtin_amdgcn_s_barrier(); FENCE(); } while (0)

// stage one K-half of A or B for tile T: 256 rows x 32 cols bf16 = 16KB, 2 GLD
#define STAGE(matB, kk, T) do {                                                \
  const int _b = (((T) & 1) << 16) + ((matB) << 15) + ((kk) << 14);            \
  const unsigned short* _g = (matB) ? gB : gA;                                 \
  const size_t _go = (size_t)(T) * BK + (size_t)(kk) * 32;                     \
  GLD16(_g + _go, smem + _b + ldsw);                                           \
  GLD16(_g + (size_t)128 * K_TOT + _go, smem + _b + 8192 + ldsw);              \
} while (0)

#define RD_A32(DST, mh, kk, bo) do {                                           \
  _Pragma("unroll")                                                            \
  for (int a_ = 0; a_ < 2; ++a_)                                               \
    _Pragma("unroll")                                                          \
    for (int ks_ = 0; ks_ < 2; ++ks_)                                          \
      DST[a_][ks_] = *reinterpret_cast<const bf16x8*>(                         \
          smem + (bo) + ((kk) << 14) +                                         \
          ((wr * 8 + ((mh) * 2 + a_) * 2 + lhi) << 10) + l15 * 64 +            \
          ((((ks_ << 1) + l32) ^ lsw) << 4));                                  \
} while (0)

#define RD_B32(DST, kk, bo) do {                                               \
  _Pragma("unroll")                                                            \
  for (int n_ = 0; n_ < 2; ++n_)                                               \
    _Pragma("unroll")                                                          \
    for (int ks_ = 0; ks_ < 2; ++ks_)                                          \
      DST[n_][ks_] = *reinterpret_cast<const bf16x8*>(                         \
          smem + (bo) + 32768 + ((kk) << 14) +                                 \
          ((wc * 4 + n_ * 2 + lhi) << 10) + l15 * 64 +                         \
          ((((ks_ << 1) + l32) ^ lsw) << 4));                                  \
} while (0)

#define MMQ32(ASET, BSET, mh) do {                                             \
  __builtin_amdgcn_s_setprio(1);                                               \
  _Pragma("unroll")                                                            \
  for (int a_ = 0; a_ < 2; ++a_) {                                             \
    _Pragma("unroll")                                                          \
    for (int n_ = 0; n_ < 2; ++n_) {                                           \
      acc[(mh) * 2 + a_][n_] = __builtin_amdgcn_mfma_f32_32x32x16_bf16(        \
          ASET[a_][0], BSET[n_][0], acc[(mh) * 2 + a_][n_], 0, 0, 0);          \
      acc[(mh) * 2 + a_][n_] = __builtin_amdgcn_mfma_f32_32x32x16_bf16(        \
          ASET[a_][1], BSET[n_][1], acc[(mh) * 2 + a_][n_], 0, 0, 0);          \
    }                                                                          \
  }                                                                            \
  __builtin_amdgcn_s_setprio(0);                                               \
} while (0)

__global__ __launch_bounds__(512, 2) void gemm_kernel(
    const unsigned short* __restrict__ xb, const unsigned short* __restrict__ wb,
    const float* __restrict__ bias, const float* __restrict__ inter,
    const float* __restrict__ lb, const int* __restrict__ eid,
    float* __restrict__ out) {
  __shared__ unsigned char smem[131072];

  const int bid = blockIdx.x;
  const int swz = (bid & 7) * 128 + (bid >> 3);   // 1024 wgs, bijective
  const int bm = swz >> 4, bn = swz & 15;         // bm-major (best FETCH map)
  const int brow = bm * BM, bcol = bn * BN;
  const int t = threadIdx.x;
  const int w = t >> 6, l = t & 63;
  const int wr = w >> 2, wc = w & 3;              // 2 x 4 wave grid, wave = 128x64 out
  const int lhi = (l >> 4) & 1;
  const int l15 = l & 15;
  const int l32 = l >> 5;
  const int lsw = (l >> 1) & 3;

  // staging source (pre-swizzled; inverse of the ds_read swizzle, rule 21).
  const int srow = t >> 2;
  const int scol = ((t & 3) ^ ((t >> 3) & 3)) << 3;
  const unsigned short* gA = xb + (size_t)(brow + srow) * K_TOT + scol;
  const unsigned short* gB = wb + (size_t)(bcol + srow) * K_TOT + scol;
  const int ldsw = w << 10;

  f32x16 acc[4][2];
#pragma unroll
  for (int i = 0; i < 4; ++i)
#pragma unroll
    for (int n = 0; n < 2; ++n)
#pragma unroll
      for (int r = 0; r < 16; ++r)
        acc[i][n][r] = 0.f;
  bf16x8 A0[2][2], A1[2][2], B0[2][2], B1[2][2];

  // prologue: tile0 all 4 halves + tile1 {B-k0, A-k0, B-k1}
  STAGE(0, 0, 0); STAGE(1, 0, 0); STAGE(0, 1, 0); STAGE(1, 1, 0);
  STAGE(1, 0, 1); STAGE(0, 0, 1); STAGE(1, 1, 1);
  asm volatile("s_waitcnt vmcnt(6)" ::: "memory");
  BARRIER();

  for (int T = 0; T < NTK; ++T) {
    const int bo = (T & 1) << 16;
    RD_A32(A0, 0, 0, bo); RD_B32(B0, 0, bo);
    if (T + 1 < NTK) STAGE(0, 1, T + 1);
    BARRIER();
    MMQ32(A0, B0, 0);
    BARRIER();
    RD_A32(A1, 1, 0, bo);
    if (T + 2 < NTK) STAGE(1, 0, T + 2);
    BARRIER();
    MMQ32(A1, B0, 1);
    BARRIER();
    RD_A32(A0, 0, 1, bo); RD_B32(B1, 1, bo);
    if (T + 2 < NTK) STAGE(0, 0, T + 2);
    BARRIER();
    MMQ32(A0, B1, 0);
    BARRIER();
    RD_A32(A1, 1, 1, bo);
    if (T + 2 < NTK) STAGE(1, 1, T + 2);
    BARRIER();
    MMQ32(A1, B1, 1);
    if (T + 2 < NTK) { asm volatile("s_waitcnt vmcnt(6)" ::: "memory"); }
    else             { asm volatile("s_waitcnt vmcnt(0)" ::: "memory"); }
    BARRIER();
  }

  // ---------------- epilogue: bias + 2.0 * inter @ lb^T ----------------
  __syncthreads();
  float* interS = reinterpret_cast<float*>(smem);           // 256 x 16 f32 (broadcast)
  float* lbS    = reinterpret_cast<float*>(smem + 16384);   // 256 x 17 f32 (padded)
  const int e = eid[brow >> 11];
  const float* interG = inter + (size_t)brow * RNK;
  const float* lbG    = lb + ((size_t)e * N_TOT + bcol) * RNK;
#pragma unroll
  for (int q = 0; q < 8; ++q) {
    const int idx = t + 512 * q;
    interS[idx] = interG[idx];
    lbS[(idx >> 4) * 17 + (idx & 15)] = lbG[idx];
  }
  __syncthreads();

  // C/D layout (32x32): col = lane&31, row = (r&3) + 8*(r>>2) + 4*(lane>>5)
  const int ccol = wc * 64 + (l & 31);
  float bv[2];
#pragma unroll
  for (int n = 0; n < 2; ++n)
    bv[n] = bias[bcol + ccol + n * 32];

#pragma unroll
  for (int ar = 0; ar < 4; ++ar) {
#pragma unroll
    for (int r = 0; r < 16; ++r) {
      const int ml = wr * 128 + ar * 32 + (r & 3) + 8 * (r >> 2) + 4 * l32;
      const float* iv = interS + ml * RNK;
      const size_t orow = (size_t)(brow + ml) * N_TOT + bcol;
#pragma unroll
      for (int n = 0; n < 2; ++n) {
        const int ol = ccol + n * 32;
        const float* lv = lbS + ol * 17;
        float d = 0.f;
#pragma unroll
        for (int rr = 0; rr < RNK; ++rr) d += iv[rr] * lv[rr];
        out[orow + ol] = acc[ar][n][r] + bv[n] + 2.0f * d;
      }
    }
  }
}

extern "C" void kernel_launch(void* const* d_in, const int* in_sizes, int n_in,
                              void* d_out, int out_size, void* d_ws, size_t ws_size,
                              hipStream_t stream) {
  const float* x    = (const float*)d_in[0];
  const int*   eid  = (const int*)d_in[1];
  const float* W    = (const float*)d_in[2];
  const float* bias = (const float*)d_in[3];
  const float* la   = (const float*)d_in[4];
  const float* lb   = (const float*)d_in[5];
  float* out = (float*)d_out;

  // workspace layout: xb (134MB) | wb (33.5MB) | inter (1MB)
  unsigned short* xb = (unsigned short*)d_ws;
  unsigned short* wb = xb + (size_t)M_TOT * K_TOT;
  float* inter = (float*)(wb + (size_t)N_TOT * K_TOT);

  aux_kernel<<<3072, 256, 0, stream>>>(x, eid, la, W, xb, wb, inter);

  gemm_kernel<<<(M_TOT / BM) * (N_TOT / BN), 512, 0, stream>>>(
      xb, wb, bias, inter, lb, eid, out);
}

// Round 16
// 749.886 us; speedup vs baseline: 16.8091x; 1.1045x over previous
//
#include <hip/hip_runtime.h>
#include <hip/hip_bf16.h>
#include <cstdint>

#define M_TOT 16384
#define K_TOT 4096
#define N_TOT 4096
#define RNK   16
#define BM 256
#define BN 256
#define BK 64
#define NTK (K_TOT / BK)   // 64 K-tiles

using bf16x8 = __attribute__((ext_vector_type(8))) __bf16;
using f32x16 = __attribute__((ext_vector_type(16))) float;

__device__ __forceinline__ unsigned short f2bf(float f) {
  union { float f; unsigned u; } v; v.f = f;
  unsigned u = v.u;
  unsigned r = (u + 0x7fffu + ((u >> 16) & 1u)) >> 16;
  return (unsigned short)r;
}

// ---- fused aux: blocks [0,2048): xb = bf16(x) + inter (la staged in LDS) ---
// ----            blocks [2048,3072): wb = bf16(W)                         ---
__global__ __launch_bounds__(256) void aux_kernel(
    const float* __restrict__ x, const int* __restrict__ eid,
    const float* __restrict__ la, const float* __restrict__ W,
    unsigned short* __restrict__ xb, unsigned short* __restrict__ wb,
    float* __restrict__ inter) {
  __shared__ float4 laS[2][512];   // 2 x 8KB: la[e] slice 16r x 128k per chunk
  const int bid = blockIdx.x;
  const int t = threadIdx.x;
  if (bid < 2048) {
    const int row0 = bid * 8;
    const int q = t >> 5, c = t & 31;       // row = row0+q, k-lane c
    const int row = row0 + q;
    const float4* xr = reinterpret_cast<const float4*>(x + (size_t)row * K_TOT);
    ushort4* xw = reinterpret_cast<ushort4*>(xb + (size_t)row * K_TOT);
    const int e = eid[row0 >> 11];
    const float4* la4 = reinterpret_cast<const float4*>(la + (size_t)e * RNK * K_TOT);
    // stage slot s -> (r = s>>5, c4 = s&31): la4[r*1024 + i*32 + c4]
    const int sr0 = t >> 5, sc0 = t & 31;            // slot t
    const int sr1 = (t + 256) >> 5, sc1 = t & 31;    // slot t+256
    float pacc[RNK];
#pragma unroll
    for (int r = 0; r < RNK; ++r) pacc[r] = 0.f;

    laS[0][t]       = la4[sr0 * (K_TOT / 4) + sc0];
    laS[0][t + 256] = la4[sr1 * (K_TOT / 4) + sc1];
    for (int i = 0; i < 32; ++i) {
      __syncthreads();                        // staged chunk i visible; prev compute done
      const int buf = i & 1;
      if (i + 1 < 32) {
        laS[buf ^ 1][t]       = la4[sr0 * (K_TOT / 4) + (i + 1) * 32 + sc0];
        laS[buf ^ 1][t + 256] = la4[sr1 * (K_TOT / 4) + (i + 1) * 32 + sc1];
      }
      const int j = c + 32 * i;
      float4 v = xr[j];
      ushort4 o;
      o.x = f2bf(v.x); o.y = f2bf(v.y); o.z = f2bf(v.z); o.w = f2bf(v.w);
      xw[j] = o;
#pragma unroll
      for (int r = 0; r < RNK; ++r) {
        float4 l4 = laS[buf][r * 32 + c];     // broadcast across q; conflict-free
        pacc[r] += v.x * l4.x + v.y * l4.y + v.z * l4.z + v.w * l4.w;
      }
    }
    // reduce over the 32 k-lanes of this row
#pragma unroll
    for (int r = 0; r < RNK; ++r) {
      float a = pacc[r];
      a += __shfl_xor(a, 1);
      a += __shfl_xor(a, 2);
      a += __shfl_xor(a, 4);
      a += __shfl_xor(a, 8);
      a += __shfl_xor(a, 16);
      pacc[r] = a;
    }
    if (c == 0) {
#pragma unroll
      for (int r = 0; r < RNK; ++r)
        inter[(size_t)row * RNK + r] = pacc[r];
    }
  } else {
    // W conversion: 1024 blocks x 256 thr x 16 float4
    const int base = (bid - 2048) * 4096;
    const float4* ws = reinterpret_cast<const float4*>(W);
    ushort4* wd = reinterpret_cast<ushort4*>(wb);
#pragma unroll
    for (int i = 0; i < 16; ++i) {
      const int j = base + t + 256 * i;
      float4 v = ws[j];
      ushort4 o;
      o.x = f2bf(v.x); o.y = f2bf(v.y); o.z = f2bf(v.z); o.w = f2bf(v.w);
      wd[j] = o;
    }
  }
}

// ---------- 256x256 8-phase GEMM, 32x32x16 MFMA + fused LoRA epilogue -------
// (exact r11 kernel -- best measured: gemm 663 us / 829 TF)
#define GLD16(gsrc, ldst)                                                      \
  __builtin_amdgcn_global_load_lds(                                            \
      (__attribute__((address_space(1))) const void*)(gsrc),                   \
      (__attribute__((address_space(3))) void*)(ldst), 16, 0, 0)

#define FENCE() asm volatile("" ::: "memory")
#define BARRIER() do { FENCE(); __builtin_amdgcn_s_barrier(); FENCE(); } while (0)

// stage one K-half of A or B for tile T: 256 rows x 32 cols bf16 = 16KB, 2 GLD
#define STAGE(matB, kk, T) do {                                                \
  const int _b = (((T) & 1) << 16) + ((matB) << 15) + ((kk) << 14);            \
  const unsigned short* _g = (matB) ? gB : gA;                                 \
  const size_t _go = (size_t)(T) * BK + (size_t)(kk) * 32;                     \
  GLD16(_g + _go, smem + _b + ldsw);                                           \
  GLD16(_g + (size_t)128 * K_TOT + _go, smem + _b + 8192 + ldsw);              \
} while (0)

#define RD_A32(DST, mh, kk, bo) do {                                           \
  _Pragma("unroll")                                                            \
  for (int a_ = 0; a_ < 2; ++a_)                                               \
    _Pragma("unroll")                                                          \
    for (int ks_ = 0; ks_ < 2; ++ks_)                                          \
      DST[a_][ks_] = *reinterpret_cast<const bf16x8*>(                         \
          smem + (bo) + ((kk) << 14) +                                         \
          ((wr * 8 + ((mh) * 2 + a_) * 2 + lhi) << 10) + l15 * 64 +            \
          ((((ks_ << 1) + l32) ^ lsw) << 4));                                  \
} while (0)

#define RD_B32(DST, kk, bo) do {                                               \
  _Pragma("unroll")                                                            \
  for (int n_ = 0; n_ < 2; ++n_)                                               \
    _Pragma("unroll")                                                          \
    for (int ks_ = 0; ks_ < 2; ++ks_)                                          \
      DST[n_][ks_] = *reinterpret_cast<const bf16x8*>(                         \
          smem + (bo) + 32768 + ((kk) << 14) +                                 \
          ((wc * 4 + n_ * 2 + lhi) << 10) + l15 * 64 +                         \
          ((((ks_ << 1) + l32) ^ lsw) << 4));                                  \
} while (0)

#define MMQ32(ASET, BSET, mh) do {                                             \
  __builtin_amdgcn_s_setprio(1);                                               \
  _Pragma("unroll")                                                            \
  for (int a_ = 0; a_ < 2; ++a_) {                                             \
    _Pragma("unroll")                                                          \
    for (int n_ = 0; n_ < 2; ++n_) {                                           \
      acc[(mh) * 2 + a_][n_] = __builtin_amdgcn_mfma_f32_32x32x16_bf16(        \
          ASET[a_][0], BSET[n_][0], acc[(mh) * 2 + a_][n_], 0, 0, 0);          \
      acc[(mh) * 2 + a_][n_] = __builtin_amdgcn_mfma_f32_32x32x16_bf16(        \
          ASET[a_][1], BSET[n_][1], acc[(mh) * 2 + a_][n_], 0, 0, 0);          \
    }                                                                          \
  }                                                                            \
  __builtin_amdgcn_s_setprio(0);                                               \
} while (0)

__global__ __launch_bounds__(512, 2) void gemm_kernel(
    const unsigned short* __restrict__ xb, const unsigned short* __restrict__ wb,
    const float* __restrict__ bias, const float* __restrict__ inter,
    const float* __restrict__ lb, const int* __restrict__ eid,
    float* __restrict__ out) {
  __shared__ unsigned char smem[131072];

  const int bid = blockIdx.x;
  const int swz = (bid & 7) * 128 + (bid >> 3);   // 1024 wgs, bijective
  const int bm = swz >> 4, bn = swz & 15;         // bm-major (best FETCH map)
  const int brow = bm * BM, bcol = bn * BN;
  const int t = threadIdx.x;
  const int w = t >> 6, l = t & 63;
  const int wr = w >> 2, wc = w & 3;              // 2 x 4 wave grid, wave = 128x64 out
  const int lhi = (l >> 4) & 1;
  const int l15 = l & 15;
  const int l32 = l >> 5;
  const int lsw = (l >> 1) & 3;

  // staging source (pre-swizzled; inverse of the ds_read swizzle, rule 21).
  const int srow = t >> 2;
  const int scol = ((t & 3) ^ ((t >> 3) & 3)) << 3;
  const unsigned short* gA = xb + (size_t)(brow + srow) * K_TOT + scol;
  const unsigned short* gB = wb + (size_t)(bcol + srow) * K_TOT + scol;
  const int ldsw = w << 10;

  f32x16 acc[4][2];
#pragma unroll
  for (int i = 0; i < 4; ++i)
#pragma unroll
    for (int n = 0; n < 2; ++n)
#pragma unroll
      for (int r = 0; r < 16; ++r)
        acc[i][n][r] = 0.f;
  bf16x8 A0[2][2], A1[2][2], B0[2][2], B1[2][2];

  // prologue: tile0 all 4 halves + tile1 {B-k0, A-k0, B-k1}
  STAGE(0, 0, 0); STAGE(1, 0, 0); STAGE(0, 1, 0); STAGE(1, 1, 0);
  STAGE(1, 0, 1); STAGE(0, 0, 1); STAGE(1, 1, 1);
  asm volatile("s_waitcnt vmcnt(6)" ::: "memory");
  BARRIER();

  for (int T = 0; T < NTK; ++T) {
    const int bo = (T & 1) << 16;
    RD_A32(A0, 0, 0, bo); RD_B32(B0, 0, bo);
    if (T + 1 < NTK) STAGE(0, 1, T + 1);
    BARRIER();
    MMQ32(A0, B0, 0);
    BARRIER();
    RD_A32(A1, 1, 0, bo);
    if (T + 2 < NTK) STAGE(1, 0, T + 2);
    BARRIER();
    MMQ32(A1, B0, 1);
    BARRIER();
    RD_A32(A0, 0, 1, bo); RD_B32(B1, 1, bo);
    if (T + 2 < NTK) STAGE(0, 0, T + 2);
    BARRIER();
    MMQ32(A0, B1, 0);
    BARRIER();
    RD_A32(A1, 1, 1, bo);
    if (T + 2 < NTK) STAGE(1, 1, T + 2);
    BARRIER();
    MMQ32(A1, B1, 1);
    if (T + 2 < NTK) { asm volatile("s_waitcnt vmcnt(6)" ::: "memory"); }
    else             { asm volatile("s_waitcnt vmcnt(0)" ::: "memory"); }
    BARRIER();
  }

  // ---------------- epilogue: bias + 2.0 * inter @ lb^T ----------------
  __syncthreads();
  float* interS = reinterpret_cast<float*>(smem);           // 256 x 16 f32 (broadcast)
  float* lbS    = reinterpret_cast<float*>(smem + 16384);   // 256 x 17 f32 (padded)
  const int e = eid[brow >> 11];
  const float* interG = inter + (size_t)brow * RNK;
  const float* lbG    = lb + ((size_t)e * N_TOT + bcol) * RNK;
#pragma unroll
  for (int q = 0; q < 8; ++q) {
    const int idx = t + 512 * q;
    interS[idx] = interG[idx];
    lbS[(idx >> 4) * 17 + (idx & 15)] = lbG[idx];
  }
  __syncthreads();

  // C/D layout (32x32): col = lane&31, row = (r&3) + 8*(r>>2) + 4*(lane>>5)
  const int ccol = wc * 64 + (l & 31);
  float bv[2];
#pragma unroll
  for (int n = 0; n < 2; ++n)
    bv[n] = bias[bcol + ccol + n * 32];

#pragma unroll
  for (int ar = 0; ar < 4; ++ar) {
#pragma unroll
    for (int r = 0; r < 16; ++r) {
      const int ml = wr * 128 + ar * 32 + (r & 3) + 8 * (r >> 2) + 4 * l32;
      const float* iv = interS + ml * RNK;
      const size_t orow = (size_t)(brow + ml) * N_TOT + bcol;
#pragma unroll
      for (int n = 0; n < 2; ++n) {
        const int ol = ccol + n * 32;
        const float* lv = lbS + ol * 17;
        float d = 0.f;
#pragma unroll
        for (int rr = 0; rr < RNK; ++rr) d += iv[rr] * lv[rr];
        out[orow + ol] = acc[ar][n][r] + bv[n] + 2.0f * d;
      }
    }
  }
}

extern "C" void kernel_launch(void* const* d_in, const int* in_sizes, int n_in,
                              void* d_out, int out_size, void* d_ws, size_t ws_size,
                              hipStream_t stream) {
  const float* x    = (const float*)d_in[0];
  const int*   eid  = (const int*)d_in[1];
  const float* W    = (const float*)d_in[2];
  const float* bias = (const float*)d_in[3];
  const float* la   = (const float*)d_in[4];
  const float* lb   = (const float*)d_in[5];
  float* out = (float*)d_out;

  // workspace layout: xb (134MB) | wb (33.5MB) | inter (1MB)
  unsigned short* xb = (unsigned short*)d_ws;
  unsigned short* wb = xb + (size_t)M_TOT * K_TOT;
  float* inter = (float*)(wb + (size_t)N_TOT * K_TOT);

  aux_kernel<<<3072, 256, 0, stream>>>(x, eid, la, W, xb, wb, inter);

  gemm_kernel<<<(M_TOT / BM) * (N_TOT / BN), 512, 0, stream>>>(
      xb, wb, bias, inter, lb, eid, out);
}

// Round 17
// 712.111 us; speedup vs baseline: 17.7007x; 1.0530x over previous
//
#include <hip/hip_runtime.h>
#include <hip/hip_bf16.h>
#include <cstdint>

#define M_TOT 16384
#define K_TOT 4096
#define N_TOT 4096
#define RNK   16
#define BM 256
#define BN 256
#define BK 64
#define NTK (K_TOT / BK)   // 64 K-tiles

using bf16x8 = __attribute__((ext_vector_type(8))) __bf16;
using f32x16 = __attribute__((ext_vector_type(16))) float;

__device__ __forceinline__ unsigned short f2bf(float f) {
  union { float f; unsigned u; } v; v.f = f;
  unsigned u = v.u;
  unsigned r = (u + 0x7fffu + ((u >> 16) & 1u)) >> 16;
  return (unsigned short)r;
}

// ---- fused aux: blocks [0,2048): xb = bf16(x) + inter (la staged in LDS) ---
// ----            blocks [2048,3072): wb = bf16(W)                         ---
__global__ __launch_bounds__(256) void aux_kernel(
    const float* __restrict__ x, const int* __restrict__ eid,
    const float* __restrict__ la, const float* __restrict__ W,
    unsigned short* __restrict__ xb, unsigned short* __restrict__ wb,
    float* __restrict__ inter) {
  __shared__ float4 laS[2][512];   // 2 x 8KB: la[e] slice 16r x 128k per chunk
  const int bid = blockIdx.x;
  const int t = threadIdx.x;
  if (bid < 2048) {
    const int row0 = bid * 8;
    const int q = t >> 5, c = t & 31;       // row = row0+q, k-lane c
    const int row = row0 + q;
    const float4* xr = reinterpret_cast<const float4*>(x + (size_t)row * K_TOT);
    ushort4* xw = reinterpret_cast<ushort4*>(xb + (size_t)row * K_TOT);
    const int e = eid[row0 >> 11];
    const float4* la4 = reinterpret_cast<const float4*>(la + (size_t)e * RNK * K_TOT);
    const int sr0 = t >> 5, sc0 = t & 31;            // stage slot t
    const int sr1 = (t + 256) >> 5, sc1 = t & 31;    // stage slot t+256
    float pacc[RNK];
#pragma unroll
    for (int r = 0; r < RNK; ++r) pacc[r] = 0.f;

    laS[0][t]       = la4[sr0 * (K_TOT / 4) + sc0];
    laS[0][t + 256] = la4[sr1 * (K_TOT / 4) + sc1];
    for (int i = 0; i < 32; ++i) {
      __syncthreads();                        // staged chunk i visible
      const int buf = i & 1;
      if (i + 1 < 32) {
        laS[buf ^ 1][t]       = la4[sr0 * (K_TOT / 4) + (i + 1) * 32 + sc0];
        laS[buf ^ 1][t + 256] = la4[sr1 * (K_TOT / 4) + (i + 1) * 32 + sc1];
      }
      const int j = c + 32 * i;
      float4 v = xr[j];
      ushort4 o;
      o.x = f2bf(v.x); o.y = f2bf(v.y); o.z = f2bf(v.z); o.w = f2bf(v.w);
      xw[j] = o;
#pragma unroll
      for (int r = 0; r < RNK; ++r) {
        float4 l4 = laS[buf][r * 32 + c];     // broadcast across q
        pacc[r] += v.x * l4.x + v.y * l4.y + v.z * l4.z + v.w * l4.w;
      }
    }
#pragma unroll
    for (int r = 0; r < RNK; ++r) {
      float a = pacc[r];
      a += __shfl_xor(a, 1);
      a += __shfl_xor(a, 2);
      a += __shfl_xor(a, 4);
      a += __shfl_xor(a, 8);
      a += __shfl_xor(a, 16);
      pacc[r] = a;
    }
    if (c == 0) {
#pragma unroll
      for (int r = 0; r < RNK; ++r)
        inter[(size_t)row * RNK + r] = pacc[r];
    }
  } else {
    const int base = (bid - 2048) * 4096;
    const float4* ws = reinterpret_cast<const float4*>(W);
    ushort4* wd = reinterpret_cast<ushort4*>(wb);
#pragma unroll
    for (int i = 0; i < 16; ++i) {
      const int j = base + t + 256 * i;
      float4 v = ws[j];
      ushort4 o;
      o.x = f2bf(v.x); o.y = f2bf(v.y); o.z = f2bf(v.z); o.w = f2bf(v.w);
      wd[j] = o;
    }
  }
}

// ---------- 256x256 GEMM, 32x32x16 MFMA, cross-barrier read-ahead -----------
// Phase p: {RD(frags for p+1); STAGE; barrier; MMQ(frags loaded at p-1)}.
// LDS pipe processes the next phase's read batch while matrix pipes run MMQ;
// the consuming MFMA is a full phase + barrier downstream of its reads.
#define GLD16(gsrc, ldst)                                                      \
  __builtin_amdgcn_global_load_lds(                                            \
      (__attribute__((address_space(1))) const void*)(gsrc),                   \
      (__attribute__((address_space(3))) void*)(ldst), 16, 0, 0)

#define FENCE() asm volatile("" ::: "memory")
#define BARRIER() do { FENCE(); __builtin_amdgcn_s_barrier(); FENCE(); } while (0)

// stage one K-half of A or B for tile T: 256 rows x 32 cols bf16 = 16KB, 2 GLD
#define STAGE(matB, kk, T) do {                                                \
  const int _b = (((T) & 1) << 16) + ((matB) << 15) + ((kk) << 14);            \
  const unsigned short* _g = (matB) ? gB : gA;                                 \
  const size_t _go = (size_t)(T) * BK + (size_t)(kk) * 32;                     \
  GLD16(_g + _go, smem + _b + ldsw);                                           \
  GLD16(_g + (size_t)128 * K_TOT + _go, smem + _b + 8192 + ldsw);              \
} while (0)

#define RD_A32(DST, mh, kk, bo) do {                                           \
  _Pragma("unroll")                                                            \
  for (int a_ = 0; a_ < 2; ++a_)                                               \
    _Pragma("unroll")                                                          \
    for (int ks_ = 0; ks_ < 2; ++ks_)                                          \
      DST[a_][ks_] = *reinterpret_cast<const bf16x8*>(                         \
          smem + (bo) + ((kk) << 14) +                                         \
          ((wr * 8 + ((mh) * 2 + a_) * 2 + lhi) << 10) + l15 * 64 +            \
          ((((ks_ << 1) + l32) ^ lsw) << 4));                                  \
} while (0)

#define RD_B32(DST, kk, bo) do {                                               \
  _Pragma("unroll")                                                            \
  for (int n_ = 0; n_ < 2; ++n_)                                               \
    _Pragma("unroll")                                                          \
    for (int ks_ = 0; ks_ < 2; ++ks_)                                          \
      DST[n_][ks_] = *reinterpret_cast<const bf16x8*>(                         \
          smem + (bo) + 32768 + ((kk) << 14) +                                 \
          ((wc * 4 + n_ * 2 + lhi) << 10) + l15 * 64 +                         \
          ((((ks_ << 1) + l32) ^ lsw) << 4));                                  \
} while (0)

#define MMQ32(ASET, BSET, mh) do {                                             \
  __builtin_amdgcn_s_setprio(1);                                               \
  _Pragma("unroll")                                                            \
  for (int a_ = 0; a_ < 2; ++a_) {                                             \
    _Pragma("unroll")                                                          \
    for (int n_ = 0; n_ < 2; ++n_) {                                           \
      acc[(mh) * 2 + a_][n_] = __builtin_amdgcn_mfma_f32_32x32x16_bf16(        \
          ASET[a_][0], BSET[n_][0], acc[(mh) * 2 + a_][n_], 0, 0, 0);          \
      acc[(mh) * 2 + a_][n_] = __builtin_amdgcn_mfma_f32_32x32x16_bf16(        \
          ASET[a_][1], BSET[n_][1], acc[(mh) * 2 + a_][n_], 0, 0, 0);          \
    }                                                                          \
  }                                                                            \
  __builtin_amdgcn_s_setprio(0);                                               \
} while (0)

__global__ __launch_bounds__(512, 2) void gemm_kernel(
    const unsigned short* __restrict__ xb, const unsigned short* __restrict__ wb,
    const float* __restrict__ bias, const float* __restrict__ inter,
    const float* __restrict__ lb, const int* __restrict__ eid,
    float* __restrict__ out) {
  __shared__ unsigned char smem[131072];

  const int bid = blockIdx.x;
  const int swz = (bid & 7) * 128 + (bid >> 3);   // 1024 wgs, bijective
  const int bm = swz >> 4, bn = swz & 15;         // bm-major (best FETCH map)
  const int brow = bm * BM, bcol = bn * BN;
  const int t = threadIdx.x;
  const int w = t >> 6, l = t & 63;
  const int wr = w >> 2, wc = w & 3;              // 2 x 4 wave grid, wave = 128x64 out
  const int lhi = (l >> 4) & 1;
  const int l15 = l & 15;
  const int l32 = l >> 5;
  const int lsw = (l >> 1) & 3;

  // staging source (pre-swizzled; inverse of the ds_read swizzle, rule 21).
  const int srow = t >> 2;
  const int scol = ((t & 3) ^ ((t >> 3) & 3)) << 3;
  const unsigned short* gA = xb + (size_t)(brow + srow) * K_TOT + scol;
  const unsigned short* gB = wb + (size_t)(bcol + srow) * K_TOT + scol;
  const int ldsw = w << 10;

  f32x16 acc[4][2];
#pragma unroll
  for (int i = 0; i < 4; ++i)
#pragma unroll
    for (int n = 0; n < 2; ++n)
#pragma unroll
      for (int r = 0; r < 16; ++r)
        acc[i][n][r] = 0.f;
  bf16x8 A0[2][2], A1[2][2], B0[2][2], B1[2][2];

  // prologue: tile0 all 4 halves + tile1 {B-k0, A-k0, B-k1}; vmcnt(6)
  // retires exactly tile0's 8 loads.
  STAGE(0, 0, 0); STAGE(1, 0, 0); STAGE(0, 1, 0); STAGE(1, 1, 0);
  STAGE(1, 0, 1); STAGE(0, 0, 1); STAGE(1, 1, 1);
  asm volatile("s_waitcnt vmcnt(6)" ::: "memory");
  BARRIER();
  // initial frags for tile0 phase0
  RD_A32(A0, 0, 0, 0); RD_B32(B0, 0, 0);

  for (int T = 0; T < NTK; ++T) {
    const int bo = (T & 1) << 16;
    const int nbo = bo ^ 0x10000;
    // ph0: RD for ph1 ; stage A-k1(T+1) ; barrier ; MMQ(mh0,k0)
    RD_A32(A1, 1, 0, bo);
    if (T + 1 < NTK) STAGE(0, 1, T + 1);
    BARRIER();
    MMQ32(A0, B0, 0);
    // ph1: RD for ph2 ; stage B-k0(T+2) ; barrier ; MMQ(mh1,k0)
    RD_A32(A0, 0, 1, bo); RD_B32(B1, 1, bo);
    if (T + 2 < NTK) STAGE(1, 0, T + 2);
    BARRIER();
    MMQ32(A1, B0, 1);
    // ph2: RD for ph3 ; stage A-k0(T+2) ; barrier ; MMQ(mh0,k1)
    RD_A32(A1, 1, 1, bo);
    if (T + 2 < NTK) STAGE(0, 0, T + 2);
    BARRIER();
    MMQ32(A0, B1, 0);
    // ph3: RD for next tile's ph0 (halves retired at T-1 boundary) ;
    // stage B-k1(T+2) ; boundary vmcnt ; barrier ; MMQ(mh1,k1)
    if (T + 1 < NTK) { RD_A32(A0, 0, 0, nbo); RD_B32(B0, 0, nbo); }
    if (T + 2 < NTK) STAGE(1, 1, T + 2);
    if (T + 2 < NTK) { asm volatile("s_waitcnt vmcnt(6)" ::: "memory"); }
    else             { asm volatile("s_waitcnt vmcnt(0)" ::: "memory"); }
    BARRIER();
    MMQ32(A1, B1, 1);
  }

  // ---------------- epilogue: bias + 2.0 * inter @ lb^T ----------------
  __syncthreads();
  float* interS = reinterpret_cast<float*>(smem);           // 256 x 16 f32 (broadcast)
  float* lbS    = reinterpret_cast<float*>(smem + 16384);   // 256 x 17 f32 (padded)
  const int e = eid[brow >> 11];
  const float* interG = inter + (size_t)brow * RNK;
  const float* lbG    = lb + ((size_t)e * N_TOT + bcol) * RNK;
#pragma unroll
  for (int q = 0; q < 8; ++q) {
    const int idx = t + 512 * q;
    interS[idx] = interG[idx];
    lbS[(idx >> 4) * 17 + (idx & 15)] = lbG[idx];
  }
  __syncthreads();

  // C/D layout (32x32): col = lane&31, row = (r&3) + 8*(r>>2) + 4*(lane>>5)
  const int ccol = wc * 64 + (l & 31);
  float bv[2];
#pragma unroll
  for (int n = 0; n < 2; ++n)
    bv[n] = bias[bcol + ccol + n * 32];

#pragma unroll
  for (int ar = 0; ar < 4; ++ar) {
#pragma unroll
    for (int r = 0; r < 16; ++r) {
      const int ml = wr * 128 + ar * 32 + (r & 3) + 8 * (r >> 2) + 4 * l32;
      const float* iv = interS + ml * RNK;
      const size_t orow = (size_t)(brow + ml) * N_TOT + bcol;
#pragma unroll
      for (int n = 0; n < 2; ++n) {
        const int ol = ccol + n * 32;
        const float* lv = lbS + ol * 17;
        float d = 0.f;
#pragma unroll
        for (int rr = 0; rr < RNK; ++rr) d += iv[rr] * lv[rr];
        out[orow + ol] = acc[ar][n][r] + bv[n] + 2.0f * d;
      }
    }
  }
}

extern "C" void kernel_launch(void* const* d_in, const int* in_sizes, int n_in,
                              void* d_out, int out_size, void* d_ws, size_t ws_size,
                              hipStream_t stream) {
  const float* x    = (const float*)d_in[0];
  const int*   eid  = (const int*)d_in[1];
  const float* W    = (const float*)d_in[2];
  const float* bias = (const float*)d_in[3];
  const float* la   = (const float*)d_in[4];
  const float* lb   = (const float*)d_in[5];
  float* out = (float*)d_out;

  // workspace layout: xb (134MB) | wb (33.5MB) | inter (1MB)
  unsigned short* xb = (unsigned short*)d_ws;
  unsigned short* wb = xb + (size_t)M_TOT * K_TOT;
  float* inter = (float*)(wb + (size_t)N_TOT * K_TOT);

  aux_kernel<<<3072, 256, 0, stream>>>(x, eid, la, W, xb, wb, inter);

  gemm_kernel<<<(M_TOT / BM) * (N_TOT / BN), 512, 0, stream>>>(
      xb, wb, bias, inter, lb, eid, out);
}